// Round 2
// baseline (70.918 us; speedup 1.0000x reference)
//
#include <hip/hip_runtime.h>

#define CI 32
#define CO 32
#define PD 64
#define QDIM 1024
#define M_TOTAL (32*4096)
#define WG_THREADS 512
#define NBLK 512
#define TILE_M 64
#define NT ((M_TOTAL/TILE_M)/NBLK)   // 4 iterations per WG

typedef float  f32x4  __attribute__((ext_vector_type(4)));
typedef __bf16 bf16x8 __attribute__((ext_vector_type(8)));
typedef __bf16 bf16x4 __attribute__((ext_vector_type(4)));

#define PL_STRIDE 72   // 64 bf16 + 8 pad -> conflict-free A-frag ds_read_b128
#define XL_STRIDE 72   // 64 f32 + 8 pad  -> <=2-way on epilogue ds_read_b128

__global__ __launch_bounds__(WG_THREADS, 4)
void cond_dense_kernel(const float* __restrict__ Xg, const float* __restrict__ Pg,
                       const float* __restrict__ Wk, float* __restrict__ outg)
{
    // double-buffered LDS: one barrier per iteration
    __shared__ __bf16 Pl[2][TILE_M * PL_STRIDE];
    __shared__ float  Xl[2][CI * XL_STRIDE];

    const int tid = threadIdx.x;
    const int l   = tid & 63;
    const int w   = tid >> 6;   // wave 0..7, owns outputs o = 4w..4w+3
    const int h   = l >> 4;     // 0..3  (k-group for A/B frags; row-group for C)
    const int c   = l & 15;     // MFMA col index
    const int di  = c >> 2;     // i (mod 4) slot
    const int dq  = c & 3;      // o (mod 4) slot

    // ---- one-time: B fragments (Wk columns) -> registers, bf16 ----
    // n-tile t covers columns q = (4t+di)*32 + 4w+dq  (i = 4t+di, o = 4w+dq)
    bf16x8 bfrag[8][2];
#pragma unroll
    for (int t = 0; t < 8; ++t) {
        const int q = (4*t + di) * CO + 4*w + dq;
#pragma unroll
        for (int s = 0; s < 2; ++s) {
            bf16x8 f;
#pragma unroll
            for (int j = 0; j < 8; ++j) {
                const int k = s*32 + h*8 + j;
                f[j] = (__bf16)Wk[k * QDIM + q];
            }
            bfrag[t][s] = f;
        }
    }

    // ---- staging assignments (coalesced f32x4 global reads) ----
    const int prow = tid >> 4;        // P rows 0..31 (and +32)
    const int pcol = (tid & 15) * 4;
    const int xrow = tid >> 3;        // X rows 0..63
    const int xcol = (tid & 7) * 4;

    f32x4 pr0, pr1, xr;
    auto load_stage = [&](int tile) {
        const float* Pb = Pg + (size_t)tile * TILE_M * PD;
        const float* Xb = Xg + (size_t)tile * TILE_M * CI;
        pr0 = *(const f32x4*)(Pb + prow * PD + pcol);
        pr1 = *(const f32x4*)(Pb + (prow + 32) * PD + pcol);
        xr  = *(const f32x4*)(Xb + xrow * CI + xcol);
    };
    auto write_lds = [&](int b) {
        bf16x4 a0, a1;
#pragma unroll
        for (int j = 0; j < 4; ++j) { a0[j] = (__bf16)pr0[j]; a1[j] = (__bf16)pr1[j]; }
        *(bf16x4*)(&Pl[b][prow * PL_STRIDE + pcol])        = a0;
        *(bf16x4*)(&Pl[b][(prow + 32) * PL_STRIDE + pcol]) = a1;
#pragma unroll
        for (int j = 0; j < 4; ++j) Xl[b][(xcol + j) * XL_STRIDE + xrow] = xr[j];
    };

    const int tile0 = blockIdx.x * NT;
    load_stage(tile0);
    write_lds(0);
    __syncthreads();

    for (int it = 0; it < NT; ++it) {
        const int tile = tile0 + it;
        const int buf  = it & 1;
        if (it + 1 < NT) load_stage(tile + 1);   // issue early (T14)

        float* outp = outg + (size_t)tile * TILE_M * CO;
#pragma unroll
        for (int sub = 0; sub < 4; ++sub) {
            const int m0 = sub * 16;
            // A-fragments: row = m0+c, k = s*32 + h*8 + j
            bf16x8 af0 = *(const bf16x8*)(&Pl[buf][(m0 + c) * PL_STRIDE + h*8]);
            bf16x8 af1 = *(const bf16x8*)(&Pl[buf][(m0 + c) * PL_STRIDE + 32 + h*8]);

            f32x4 acc[8] = {};
#pragma unroll
            for (int t = 0; t < 8; ++t) {
                acc[t] = __builtin_amdgcn_mfma_f32_16x16x32_bf16(af0, bfrag[t][0], acc[t], 0, 0, 0);
                acc[t] = __builtin_amdgcn_mfma_f32_16x16x32_bf16(af1, bfrag[t][1], acc[t], 0, 0, 0);
            }
            // epilogue: out[m, 4w+dq] = sum_i relu(W[m,i,4w+dq]) * X[m,i]
            // lane holds W rows m0+h*4+r, i = 4t+di; X read transposed (4 m's per b128)
            f32x4 part = {};
#pragma unroll
            for (int t = 0; t < 8; ++t) {
                const int i = 4*t + di;
                f32x4 xv = *(const f32x4*)(&Xl[buf][i * XL_STRIDE + m0 + h*4]);
#pragma unroll
                for (int r = 0; r < 4; ++r)
                    part[r] += fmaxf(acc[t][r], 0.0f) * xv[r];
            }
            // transpose-reduce over di (lane bits 2,3): 3 shfl, no final select.
            // step1 (xor 4): lane g keeps comps {g&1, (g&1)+2} summed over {g, g^1}
            // step2 (xor 8): lane g keeps comp g summed over all 4 di-lanes
            const bool b0 = (di & 1) != 0, b1 = (di & 2) != 0;
            const float lo_k = b0 ? part[1] : part[0];
            const float lo_s = b0 ? part[0] : part[1];
            const float hi_k = b0 ? part[3] : part[2];
            const float hi_s = b0 ? part[2] : part[3];
            const float u = lo_k + __shfl_xor(lo_s, 4);
            const float v = hi_k + __shfl_xor(hi_s, 4);
            const float keep = b1 ? v : u;
            const float send = b1 ? u : v;
            const float res = keep + __shfl_xor(send, 8);
            // lane (h,di,dq) writes row m0+4h+di, col 4w+dq
            outp[(m0 + h*4 + di) * CO + w*4 + dq] = res;
        }

        if (it + 1 < NT) {
            write_lds(buf ^ 1);
            __syncthreads();
        }
    }
}

extern "C" void kernel_launch(void* const* d_in, const int* in_sizes, int n_in,
                              void* d_out, int out_size, void* d_ws, size_t ws_size,
                              hipStream_t stream)
{
    const float* X  = (const float*)d_in[0];
    const float* P  = (const float*)d_in[1];
    const float* Wk = (const float*)d_in[2];
    float* out = (float*)d_out;
    cond_dense_kernel<<<dim3(NBLK), dim3(WG_THREADS), 0, stream>>>(X, P, Wk, out);
}

// Round 3
// 61.065 us; speedup vs baseline: 1.1614x; 1.1614x over previous
//
#include <hip/hip_runtime.h>

#define CI 32
#define CO 32
#define PD 64
#define QDIM 1024
#define M_TOTAL (32*4096)
#define WG_THREADS 512
#define NBLK 512
#define TILE_M 64
#define NT ((M_TOTAL/TILE_M)/NBLK)   // 4 iterations per WG

typedef float  f32x4  __attribute__((ext_vector_type(4)));
typedef __bf16 bf16x8 __attribute__((ext_vector_type(8)));
typedef __bf16 bf16x4 __attribute__((ext_vector_type(4)));

#define PL_STRIDE 72   // 64 bf16 + 8 pad
#define XL_STRIDE 72   // 64 f32 + 8 pad
#define OL_STRIDE 44   // 32 f32 + 12 pad: rows 176B (16B-aligned), 2-way-free banks

__global__ __launch_bounds__(WG_THREADS, 4)
void cond_dense_kernel(const float* __restrict__ Xg, const float* __restrict__ Pg,
                       const float* __restrict__ Wk, float* __restrict__ outg)
{
    __shared__ __bf16 Pl[TILE_M * PL_STRIDE];   // 9216 B
    __shared__ float  Xl[CI * XL_STRIDE];       // 9216 B
    __shared__ float  Ol[TILE_M * OL_STRIDE];   // 11264 B  (output staging)

    const int tid = threadIdx.x;
    const int l   = tid & 63;
    const int w   = tid >> 6;   // wave 0..7, owns outputs o = 4w..4w+3
    const int h   = l >> 4;     // 0..3
    const int c   = l & 15;     // MFMA col index
    const int di  = c >> 2;     // i (mod 4) slot
    const int dq  = c & 3;      // o (mod 4) slot

    // ---- one-time: B fragments (Wk columns) -> registers, bf16 ----
    bf16x8 bfrag[8][2];
#pragma unroll
    for (int t = 0; t < 8; ++t) {
        const int q = (4*t + di) * CO + 4*w + dq;
#pragma unroll
        for (int s = 0; s < 2; ++s) {
            bf16x8 f;
#pragma unroll
            for (int j = 0; j < 8; ++j) {
                const int k = s*32 + h*8 + j;
                f[j] = (__bf16)Wk[k * QDIM + q];
            }
            bfrag[t][s] = f;
        }
    }

    // ---- staging assignments (coalesced f32x4 global reads) ----
    const int prow = tid >> 4;        // P rows 0..31 (and +32)
    const int pcol = (tid & 15) * 4;
    const int xrow = tid >> 3;        // X rows 0..63
    const int xcol = (tid & 7) * 4;

    f32x4 pr0, pr1, xr;
    auto load_stage = [&](int tile) {
        const float* Pb = Pg + (size_t)tile * TILE_M * PD;
        const float* Xb = Xg + (size_t)tile * TILE_M * CI;
        pr0 = *(const f32x4*)(Pb + prow * PD + pcol);
        pr1 = *(const f32x4*)(Pb + (prow + 32) * PD + pcol);
        xr  = *(const f32x4*)(Xb + xrow * CI + xcol);
    };
    auto write_lds = [&]() {
        bf16x4 a0, a1;
#pragma unroll
        for (int j = 0; j < 4; ++j) { a0[j] = (__bf16)pr0[j]; a1[j] = (__bf16)pr1[j]; }
        *(bf16x4*)(&Pl[prow * PL_STRIDE + pcol])        = a0;
        *(bf16x4*)(&Pl[(prow + 32) * PL_STRIDE + pcol]) = a1;
#pragma unroll
        for (int j = 0; j < 4; ++j) Xl[(xcol + j) * XL_STRIDE + xrow] = xr[j];
    };

    const int tile0 = blockIdx.x * NT;
    load_stage(tile0);
    write_lds();
    __syncthreads();

    for (int it = 0; it < NT; ++it) {
        const int tile = tile0 + it;
        if (it + 1 < NT) load_stage(tile + 1);   // issue next tile's loads early (T14)

#pragma unroll
        for (int sub = 0; sub < 4; ++sub) {
            const int m0 = sub * 16;
            bf16x8 af0 = *(const bf16x8*)(&Pl[(m0 + c) * PL_STRIDE + h*8]);
            bf16x8 af1 = *(const bf16x8*)(&Pl[(m0 + c) * PL_STRIDE + 32 + h*8]);

            f32x4 acc[8] = {};
#pragma unroll
            for (int t = 0; t < 8; ++t) {
                acc[t] = __builtin_amdgcn_mfma_f32_16x16x32_bf16(af0, bfrag[t][0], acc[t], 0, 0, 0);
                acc[t] = __builtin_amdgcn_mfma_f32_16x16x32_bf16(af1, bfrag[t][1], acc[t], 0, 0, 0);
            }
            // epilogue: out[m, 4w+dq] = sum_i relu(W[m,i,4w+dq]) * X[m,i]
            f32x4 part = {};
#pragma unroll
            for (int t = 0; t < 8; ++t) {
                const int i = 4*t + di;
                f32x4 xv = *(const f32x4*)(&Xl[i * XL_STRIDE + m0 + h*4]);
#pragma unroll
                for (int r = 0; r < 4; ++r)
                    part[r] += fmaxf(acc[t][r], 0.0f) * xv[r];
            }
            // transpose-reduce over di (lane bits 2,3): 3 shfl, no final select
            const bool b0 = (di & 1) != 0, b1 = (di & 2) != 0;
            const float lo_k = b0 ? part[1] : part[0];
            const float lo_s = b0 ? part[0] : part[1];
            const float hi_k = b0 ? part[3] : part[2];
            const float hi_s = b0 ? part[2] : part[3];
            const float u = lo_k + __shfl_xor(lo_s, 4);
            const float v = hi_k + __shfl_xor(hi_s, 4);
            const float keep = b1 ? v : u;
            const float send = b1 ? u : v;
            const float res = keep + __shfl_xor(send, 8);
            // stage to LDS (banks: (16h+12di+4w+dq)%32 -> 2-way, free)
            Ol[(m0 + h*4 + di) * OL_STRIDE + w*4 + dq] = res;
        }

        __syncthreads();   // Ol complete; Pl/Xl reads complete

        // coalesced store: each wave writes 1KB contiguous, full 128B lines
        {
            float* outp = outg + (size_t)tile * TILE_M * CO;
            const int row = tid >> 3, col = (tid & 7) * 4;
            f32x4 o = *(const f32x4*)(&Ol[row * OL_STRIDE + col]);
            *(f32x4*)(outp + tid * 4) = o;
        }

        if (it + 1 < NT) {
            write_lds();          // safe: Pl/Xl reads drained at barrier above
            __syncthreads();      // staging visible; Ol reads drained
        }
    }
}

extern "C" void kernel_launch(void* const* d_in, const int* in_sizes, int n_in,
                              void* d_out, int out_size, void* d_ws, size_t ws_size,
                              hipStream_t stream)
{
    const float* X  = (const float*)d_in[0];
    const float* P  = (const float*)d_in[1];
    const float* Wk = (const float*)d_in[2];
    float* out = (float*)d_out;
    cond_dense_kernel<<<dim3(NBLK), dim3(WG_THREADS), 0, stream>>>(X, P, Wk, out);
}

// Round 4
// 39.769 us; speedup vs baseline: 1.7833x; 1.5355x over previous
//
#include <hip/hip_runtime.h>

#define CI 32
#define CO 32
#define PD 64
#define QDIM 1024
#define M_TOTAL (32*4096)
#define WG_THREADS 512
#define NBLK 512
#define TILE_M 64
#define NT ((M_TOTAL/TILE_M)/NBLK)   // 4 iterations per WG

typedef float  f32x4  __attribute__((ext_vector_type(4)));
typedef __bf16 bf16x8 __attribute__((ext_vector_type(8)));
typedef __bf16 bf16x4 __attribute__((ext_vector_type(4)));

#define PL_STRIDE 72   // 64 bf16 + 8 pad
#define XL_STRIDE 72   // 64 f32 + 8 pad
#define OL_STRIDE 44   // 32 f32 + 12 pad

// ---- one-time: Wk [64][1024] f32  ->  wsT [1024][64] bf16 (column-major Wk) ----
__global__ __launch_bounds__(256)
void wk_transpose_kernel(const float* __restrict__ Wk, __bf16* __restrict__ wsT)
{
    __shared__ float tile[64][68];
    const int q0 = blockIdx.x * 64;
    const int t  = threadIdx.x;
#pragma unroll
    for (int rr = 0; rr < 4; ++rr) {
        const int k = (t >> 4) + rr * 16;
        const int cc = (t & 15) * 4;
        f32x4 v = *(const f32x4*)(Wk + (size_t)k * QDIM + q0 + cc);
        tile[k][cc] = v[0]; tile[k][cc+1] = v[1]; tile[k][cc+2] = v[2]; tile[k][cc+3] = v[3];
    }
    __syncthreads();
    const int qq = t >> 2, ks = (t & 3) * 16;
    bf16x8 o0, o1;
#pragma unroll
    for (int j = 0; j < 8; ++j) { o0[j] = (__bf16)tile[ks + j][qq]; o1[j] = (__bf16)tile[ks + 8 + j][qq]; }
    *(bf16x8*)(wsT + (size_t)(q0 + qq) * PD + ks)     = o0;
    *(bf16x8*)(wsT + (size_t)(q0 + qq) * PD + ks + 8) = o1;
}

__global__ __launch_bounds__(WG_THREADS, 4)
void cond_dense_kernel(const float* __restrict__ Xg, const float* __restrict__ Pg,
                       const __bf16* __restrict__ wsT, float* __restrict__ outg)
{
    __shared__ __bf16 Pl[TILE_M * PL_STRIDE];   // 9216 B
    __shared__ float  Xl[CI * XL_STRIDE];       // 9216 B
    __shared__ float  Ol[TILE_M * OL_STRIDE];   // 11264 B

    const int tid = threadIdx.x;
    const int l   = tid & 63;
    const int w   = tid >> 6;   // wave 0..7, owns outputs o = 4w..4w+3
    const int h   = l >> 4;     // 0..3
    const int c   = l & 15;     // MFMA col index
    const int di  = c >> 2;     // i (mod 4) slot
    const int dq  = c & 3;      // o (mod 4) slot

    // ---- B fragments: 16-byte vector loads from pre-transposed bf16 Wk ----
    // frag (t,s) = wsT[q(t)][s*32 + h*8 .. +8],  q = (4t+di)*CO + 4w+dq
    bf16x8 bfA[4][2], bfB[4][2];
#pragma unroll
    for (int tt = 0; tt < 4; ++tt) {
        const int qA = (4*tt + di) * CO + 4*w + dq;
        const int qB = (4*(tt+4) + di) * CO + 4*w + dq;
#pragma unroll
        for (int s = 0; s < 2; ++s) {
            bfA[tt][s] = *(const bf16x8*)(wsT + (size_t)qA * PD + s*32 + h*8);
            bfB[tt][s] = *(const bf16x8*)(wsT + (size_t)qB * PD + s*32 + h*8);
        }
    }

    // ---- staging assignments (coalesced f32x4 global reads) ----
    const int prow = tid >> 4;        // P rows 0..31 (and +32)
    const int pcol = (tid & 15) * 4;
    const int xrow = tid >> 3;        // X rows 0..63
    const int xcol = (tid & 7) * 4;

    f32x4 pr0, pr1, xr;
    auto load_stage = [&](int tile) {
        const float* Pb = Pg + (size_t)tile * TILE_M * PD;
        const float* Xb = Xg + (size_t)tile * TILE_M * CI;
        pr0 = *(const f32x4*)(Pb + prow * PD + pcol);
        pr1 = *(const f32x4*)(Pb + (prow + 32) * PD + pcol);
        xr  = *(const f32x4*)(Xb + xrow * CI + xcol);
    };
    auto write_lds = [&]() {
        bf16x4 a0, a1;
#pragma unroll
        for (int j = 0; j < 4; ++j) { a0[j] = (__bf16)pr0[j]; a1[j] = (__bf16)pr1[j]; }
        *(bf16x4*)(&Pl[prow * PL_STRIDE + pcol])        = a0;
        *(bf16x4*)(&Pl[(prow + 32) * PL_STRIDE + pcol]) = a1;
#pragma unroll
        for (int j = 0; j < 4; ++j) Xl[(xcol + j) * XL_STRIDE + xrow] = xr[j];
    };

    const int tile0 = blockIdx.x * NT;
    load_stage(tile0);
    write_lds();
    __syncthreads();

    for (int it = 0; it < NT; ++it) {
        const int tile = tile0 + it;
        if (it + 1 < NT) load_stage(tile + 1);   // issue next tile's loads early (T14)

#pragma unroll
        for (int sub = 0; sub < 4; ++sub) {
            const int m0 = sub * 16;
            bf16x8 af0 = *(const bf16x8*)(&Pl[(m0 + c) * PL_STRIDE + h*8]);
            bf16x8 af1 = *(const bf16x8*)(&Pl[(m0 + c) * PL_STRIDE + 32 + h*8]);

            f32x4 part = {};
            // ---- t-half A (i = 4t+di, t=0..3): acc[4] keeps peak VGPR < 128 ----
            {
                f32x4 acc[4] = {};
#pragma unroll
                for (int tt = 0; tt < 4; ++tt) {
                    acc[tt] = __builtin_amdgcn_mfma_f32_16x16x32_bf16(af0, bfA[tt][0], acc[tt], 0, 0, 0);
                    acc[tt] = __builtin_amdgcn_mfma_f32_16x16x32_bf16(af1, bfA[tt][1], acc[tt], 0, 0, 0);
                }
#pragma unroll
                for (int tt = 0; tt < 4; ++tt) {
                    const int i = 4*tt + di;
                    f32x4 xv = *(const f32x4*)(&Xl[i * XL_STRIDE + m0 + h*4]);
#pragma unroll
                    for (int r = 0; r < 4; ++r)
                        part[r] += fmaxf(acc[tt][r], 0.0f) * xv[r];
                }
            }
            // ---- t-half B (t=4..7) ----
            {
                f32x4 acc[4] = {};
#pragma unroll
                for (int tt = 0; tt < 4; ++tt) {
                    acc[tt] = __builtin_amdgcn_mfma_f32_16x16x32_bf16(af0, bfB[tt][0], acc[tt], 0, 0, 0);
                    acc[tt] = __builtin_amdgcn_mfma_f32_16x16x32_bf16(af1, bfB[tt][1], acc[tt], 0, 0, 0);
                }
#pragma unroll
                for (int tt = 0; tt < 4; ++tt) {
                    const int i = 4*(tt+4) + di;
                    f32x4 xv = *(const f32x4*)(&Xl[i * XL_STRIDE + m0 + h*4]);
#pragma unroll
                    for (int r = 0; r < 4; ++r)
                        part[r] += fmaxf(acc[tt][r], 0.0f) * xv[r];
                }
            }
            // transpose-reduce over di (lane bits 2,3): 3 shfl, no final select
            const bool b0 = (di & 1) != 0, b1 = (di & 2) != 0;
            const float lo_k = b0 ? part[1] : part[0];
            const float lo_s = b0 ? part[0] : part[1];
            const float hi_k = b0 ? part[3] : part[2];
            const float hi_s = b0 ? part[2] : part[3];
            const float u = lo_k + __shfl_xor(lo_s, 4);
            const float v = hi_k + __shfl_xor(hi_s, 4);
            const float keep = b1 ? v : u;
            const float send = b1 ? u : v;
            const float res = keep + __shfl_xor(send, 8);
            Ol[(m0 + h*4 + di) * OL_STRIDE + w*4 + dq] = res;
        }

        __syncthreads();   // Ol complete; Pl/Xl reads complete

        // coalesced store: each wave writes 1KB contiguous, full 128B lines
        {
            float* outp = outg + (size_t)tile * TILE_M * CO;
            const int row = tid >> 3, col = (tid & 7) * 4;
            f32x4 o = *(const f32x4*)(&Ol[row * OL_STRIDE + col]);
            *(f32x4*)(outp + tid * 4) = o;
        }

        if (it + 1 < NT) {
            write_lds();
            __syncthreads();
        }
    }
}

extern "C" void kernel_launch(void* const* d_in, const int* in_sizes, int n_in,
                              void* d_out, int out_size, void* d_ws, size_t ws_size,
                              hipStream_t stream)
{
    const float* X  = (const float*)d_in[0];
    const float* P  = (const float*)d_in[1];
    const float* Wk = (const float*)d_in[2];
    float* out = (float*)d_out;
    __bf16* wsT = (__bf16*)d_ws;   // 1024*64*2 = 128 KB

    wk_transpose_kernel<<<dim3(QDIM / 64), dim3(256), 0, stream>>>(Wk, wsT);
    cond_dense_kernel<<<dim3(NBLK), dim3(WG_THREADS), 0, stream>>>(X, P, wsT, out);
}